// Round 9
// baseline (132.922 us; speedup 1.0000x reference)
//
#include <hip/hip_runtime.h>
#include <hip/hip_bf16.h>

#define B 16
#define L 128
#define H 256
#define H2 512
#define P 16
#define EPSF 1e-8f
#define LDSTR 72   // shorts per LDS row: 64 + 8 pad

typedef __attribute__((ext_vector_type(8))) short short8;
typedef __attribute__((ext_vector_type(4))) short short4v;
typedef __attribute__((ext_vector_type(4))) float f32x4;

__device__ __forceinline__ short f2bf(float x) {
    unsigned u = __builtin_bit_cast(unsigned, x);
    u += 0x7fffu + ((u >> 16) & 1u);   // RNE; inputs finite
    return (short)(u >> 16);
}
__device__ __forceinline__ float bf2f(short s) {
    unsigned u = ((unsigned)(unsigned short)s) << 16;
    return __builtin_bit_cast(float, u);
}
__device__ __forceinline__ short8 pack8(float4 x, float4 y) {
    short8 s;
    s[0] = f2bf(x.x); s[1] = f2bf(x.y); s[2] = f2bf(x.z); s[3] = f2bf(x.w);
    s[4] = f2bf(y.x); s[5] = f2bf(y.y); s[6] = f2bf(y.z); s[7] = f2bf(y.w);
    return s;
}
__device__ __forceinline__ float dot4(float4 v) {
    return v.x * v.x + v.y * v.y + v.z * v.z + v.w * v.w;
}
__device__ __forceinline__ float4 mul4(float4 a, float4 b) {
    return make_float4(a.x * b.x, a.y * b.y, a.z * b.z, a.w * b.w);
}

// ---- K1: attention, wave-per-16x16-tile, no LDS (R7-identical numerics) ----
__global__ void __launch_bounds__(64) k_att_v3(
        const float* __restrict__ q1, const float* __restrict__ q2,
        float* __restrict__ att_fw, float* __restrict__ att_bw,
        float* __restrict__ attsum) {
    int bx = blockIdx.x;
    int b = bx >> 1, dir = bx & 1;
    int m0 = blockIdx.y * 16, n0 = blockIdx.z * 16;
    int l = threadIdx.x, q = l >> 4, coll = l & 15;
    size_t bL = (size_t)b * L;

    const float* arow = q1 + (bL + m0 + coll) * H2 + dir * H;
    const float* brow = q2 + (bL + n0 + coll) * H2 + dir * H;

    f32x4 acc = (f32x4){0.f, 0.f, 0.f, 0.f};
    float na = 0.f, nc = 0.f;
#pragma unroll
    for (int ks = 0; ks < 8; ks++) {
        int koff = ks * 32 + q * 8;
        float4 a0 = *(const float4*)(arow + koff);
        float4 a1 = *(const float4*)(arow + koff + 4);
        float4 b0 = *(const float4*)(brow + koff);
        float4 b1 = *(const float4*)(brow + koff + 4);
        na += dot4(a0) + dot4(a1);
        nc += dot4(b0) + dot4(b1);
        short8 af = pack8(a0, a1);
        short8 bf = pack8(b0, b1);
        acc = __builtin_amdgcn_mfma_f32_16x16x32_bf16(af, bf, acc, 0, 0, 0);
    }
    na += __shfl_xor(na, 16); na += __shfl_xor(na, 32);
    nc += __shfl_xor(nc, 16); nc += __shfl_xor(nc, 32);
    float na_s = sqrtf(na), nc_s = sqrtf(nc);

    float* attout = dir ? att_bw : att_fw;
    float rsum[4];
#pragma unroll
    for (int r = 0; r < 4; r++) {
        float nar = __shfl(na_s, (l & 48) + q * 4 + r);
        float den = nar * nc_s;
        den = den > EPSF ? den : EPSF;
        float a = acc[r] / den;
        attout[(bL + m0 + q * 4 + r) * L + n0 + coll] = a;
        rsum[r] = a;
    }
    if (dir == 0) {
#pragma unroll
        for (int off = 1; off < 16; off <<= 1)
#pragma unroll
            for (int r = 0; r < 4; r++)
                rsum[r] += __shfl_xor(rsum[r], off, 16);
        if (coll == 0)
#pragma unroll
            for (int r = 0; r < 4; r++)
                atomicAdd(&attsum[bL + m0 + q * 4 + r], rsum[r]);
    }
}

// ---- K2: weighted mean (bw uses fw row-sum, per reference) + max of att*q2 --
__global__ void __launch_bounds__(256) k_meanmax_v3(
        const float* __restrict__ q2,
        const float* __restrict__ att_fw, const float* __restrict__ att_bw,
        const float* __restrict__ attsum,
        float* __restrict__ mean_fw, float* __restrict__ mean_bw,
        float* __restrict__ maxat_fw, float* __restrict__ maxat_bw) {
    int bd = blockIdx.x;
    int b = bd >> 1, dir = bd & 1;
    int i0 = blockIdx.y * 4;
    int t = threadIdx.x;
    int wave = t >> 6, l = t & 63;
    size_t bL = (size_t)b * L;

    __shared__ float at[4][L];
    __shared__ float Ss[4];
    __shared__ f32x4 red[4][64][4];

    const float* att = dir ? att_bw : att_fw;
    for (int v = t; v < 4 * L; v += 256)
        at[v >> 7][v & 127] = att[(bL + i0 + (v >> 7)) * L + (v & 127)];
    if (t < 4) {
        float s = attsum[bL + i0 + t];
        Ss[t] = s > EPSF ? s : EPSF;
    }
    __syncthreads();

    f32x4 sum[4], mx[4];
#pragma unroll
    for (int r = 0; r < 4; r++) {
        sum[r] = (f32x4){0.f, 0.f, 0.f, 0.f};
        mx[r] = (f32x4){-INFINITY, -INFINITY, -INFINITY, -INFINITY};
    }
    const float* q2b = q2 + bL * H2 + dir * H;
    for (int jj = 0; jj < 32; jj++) {
        int j = wave * 32 + jj;
        float4 c = *(const float4*)(q2b + (size_t)j * H2 + l * 4);
#pragma unroll
        for (int r = 0; r < 4; r++) {
            float w = at[r][j];
            f32x4 v = { w * c.x, w * c.y, w * c.z, w * c.w };
            sum[r] += v;
            mx[r][0] = fmaxf(mx[r][0], v[0]);
            mx[r][1] = fmaxf(mx[r][1], v[1]);
            mx[r][2] = fmaxf(mx[r][2], v[2]);
            mx[r][3] = fmaxf(mx[r][3], v[3]);
        }
    }
    float* meanout = dir ? mean_bw : mean_fw;
    float* maxout = dir ? maxat_bw : maxat_fw;
    for (int rr = 0; rr < 2; rr++) {
        __syncthreads();
        red[wave][l][0] = sum[rr * 2];
        red[wave][l][1] = mx[rr * 2];
        red[wave][l][2] = sum[rr * 2 + 1];
        red[wave][l][3] = mx[rr * 2 + 1];
        __syncthreads();
        if (t < 128) {
            int r2 = t >> 6;
            int lane = t & 63;
            f32x4 s = red[0][lane][r2 * 2];
            f32x4 m = red[0][lane][r2 * 2 + 1];
            for (int w = 1; w < 4; w++) {
                s += red[w][lane][r2 * 2];
                f32x4 m2 = red[w][lane][r2 * 2 + 1];
                m[0] = fmaxf(m[0], m2[0]);
                m[1] = fmaxf(m[1], m2[1]);
                m[2] = fmaxf(m[2], m2[2]);
                m[3] = fmaxf(m[3], m2[3]);
            }
            int row = i0 + rr * 2 + r2;
            float inv = 1.f / Ss[rr * 2 + r2];
            size_t o = (bL + row) * H + lane * 4;
            *(f32x4*)(meanout + o) = s * inv;
            *(f32x4*)(maxout + o) = m;
        }
    }
}

// ---- K3: six cos_full pieces, fp32 (R7-identical per-thread math) ----------
// Grid (B*16, 6): block = (b, 8 i-rows, piece). 256 thr: p = t>>4, l = t&15.
__global__ void __launch_bounds__(256) k_cosfull_v3(
        const float* __restrict__ q1, const float* __restrict__ q2,
        const float* __restrict__ mean_fw, const float* __restrict__ mean_bw,
        const float* __restrict__ maxat_fw, const float* __restrict__ maxat_bw,
        const float* __restrict__ W, float* __restrict__ out) {
    int bg = blockIdx.x;
    int b = bg >> 4;
    int i0 = (bg & 15) * 8;
    int piece = blockIdx.y;
    int t = threadIdx.x;
    int p = t >> 4, l = t & 15;
    size_t bL = (size_t)b * L;

    int widx, colb, dir, cstride;
    const float* cptr;
    switch (piece) {
        case 0: widx = 0; colb = 0;   dir = 0; cptr = q2 + (bL + L - 1) * H2;  cstride = 0; break;
        case 1: widx = 1; colb = 16;  dir = 1; cptr = q2 + bL * H2 + H;        cstride = 0; break;
        case 2: widx = 4; colb = 64;  dir = 0; cptr = mean_fw + bL * H;        cstride = H; break;
        case 3: widx = 5; colb = 80;  dir = 1; cptr = mean_bw + bL * H;        cstride = H; break;
        case 4: widx = 6; colb = 96;  dir = 0; cptr = maxat_fw + bL * H;       cstride = H; break;
        default: widx = 7; colb = 112; dir = 1; cptr = maxat_bw + bL * H;      cstride = H; break;
    }
    const float* wrow = W + ((size_t)widx * P + p) * H;
    float wsq[16];
#pragma unroll
    for (int k = 0; k < 16; k++) {
        float wv = wrow[l + 16 * k];
        wsq[k] = wv * wv;
    }
    for (int ii = 0; ii < 8; ii++) {
        int i = i0 + ii;
        const float* r1 = q1 + (bL + i) * H2 + dir * H;
        const float* crow = cptr + (size_t)i * cstride;
        float num = 0, na = 0, nc = 0;
#pragma unroll
        for (int k = 0; k < 16; k++) {
            int h = l + 16 * k;
            float a = r1[h];
            float c = crow[h];
            num += a * c * wsq[k];
            na  += a * a * wsq[k];
            nc  += c * c * wsq[k];
        }
        for (int off = 8; off; off >>= 1) {
            num += __shfl_down(num, off, 16);
            na  += __shfl_down(na,  off, 16);
            nc  += __shfl_down(nc,  off, 16);
        }
        if (l == 0) {
            float den = sqrtf(na) * sqrtf(nc);
            den = den > EPSF ? den : EPSF;
            out[(bL + i) * 128 + colb + p] = num / den;
        }
    }
}

// ---- K4: cos_maxpool, B in LDS (w-folded), A-frags from global,
//          norms CONSISTENT with the bf16 values fed to MFMA ----------------
__global__ void __launch_bounds__(256) k_maxpool_v2(
        const float* __restrict__ q1, const float* __restrict__ q2,
        const float* __restrict__ W, float* __restrict__ out) {
    int bd = blockIdx.x;
    int b = bd >> 1, dir = bd & 1;
    int p = blockIdx.y;
    int t = threadIdx.x;
    int wave = t >> 6, l = t & 63;
    int q = l >> 4, coll = l & 15;
    int m0 = blockIdx.z * 64 + wave * 16;
    size_t bL = (size_t)b * L;

    __shared__ short Bs[128 * LDSTR];
    __shared__ float wf[H];
    __shared__ float ncs[128];

    if (t < 64)
        *(float4*)(wf + t * 4) =
            *(const float4*)(W + ((size_t)(2 + dir) * P + p) * H + t * 4);
    __syncthreads();

    f32x4 acc[8];
#pragma unroll
    for (int nt = 0; nt < 8; nt++) acc[nt] = (f32x4){0.f, 0.f, 0.f, 0.f};
    float ncp = 0.f, nap = 0.f;

    int brow = t >> 1, bc0 = (t & 1) * 32;
    const float* q1b = q1 + bL * H2 + dir * H;
    const float* q2b = q2 + bL * H2 + dir * H;
    const float* arow = q1b + (size_t)(m0 + coll) * H2;
    const float* brp = q2b + (size_t)brow * H2;

    for (int kt = 0; kt < 4; kt++) {
        int k0 = kt * 64;
#pragma unroll
        for (int cc = 0; cc < 8; cc++) {
            float4 v = *(const float4*)(brp + k0 + bc0 + cc * 4);
            float4 wv4 = *(const float4*)(wf + k0 + bc0 + cc * 4);
            float4 x = mul4(v, wv4);
            short4v s = { f2bf(x.x), f2bf(x.y), f2bf(x.z), f2bf(x.w) };
            *(short4v*)(Bs + brow * LDSTR + bc0 + cc * 4) = s;
            float f0 = bf2f(s[0]), f1 = bf2f(s[1]), f2v = bf2f(s[2]), f3 = bf2f(s[3]);
            ncp += f0 * f0 + f1 * f1 + f2v * f2v + f3 * f3;
        }
        __syncthreads();
#pragma unroll
        for (int ks = 0; ks < 2; ks++) {
            int koff = ks * 32 + q * 8;
            float4 a0 = *(const float4*)(arow + k0 + koff);
            float4 a1 = *(const float4*)(arow + k0 + koff + 4);
            float4 w0 = *(const float4*)(wf + k0 + koff);
            float4 w1 = *(const float4*)(wf + k0 + koff + 4);
            float4 e0 = mul4(a0, w0), e1 = mul4(a1, w1);
            short8 af = pack8(e0, e1);
#pragma unroll
            for (int j = 0; j < 8; j++) {
                float f = bf2f(af[j]);
                nap += f * f;
            }
#pragma unroll
            for (int nt = 0; nt < 8; nt++) {
                short8 bf = *(const short8*)(Bs + (nt * 16 + coll) * LDSTR + koff);
                acc[nt] = __builtin_amdgcn_mfma_f32_16x16x32_bf16(af, bf, acc[nt], 0, 0, 0);
            }
        }
        __syncthreads();
    }
    ncp += __shfl_xor(ncp, 1);
    if ((t & 1) == 0) ncs[brow] = sqrtf(ncp);
    nap += __shfl_xor(nap, 16);
    nap += __shfl_xor(nap, 32);
    float na_s = sqrtf(nap);
    __syncthreads();

    float nar[4];
#pragma unroll
    for (int r = 0; r < 4; r++)
        nar[r] = __shfl(na_s, (l & 48) + q * 4 + r);
    float rmax[4] = {-INFINITY, -INFINITY, -INFINITY, -INFINITY};
#pragma unroll
    for (int nt = 0; nt < 8; nt++) {
        float ncv = ncs[nt * 16 + coll];
#pragma unroll
        for (int r = 0; r < 4; r++) {
            float den = fmaxf(nar[r] * ncv, EPSF);
            rmax[r] = fmaxf(rmax[r], acc[nt][r] / den);
        }
    }
#pragma unroll
    for (int off = 1; off < 16; off <<= 1)
#pragma unroll
        for (int r = 0; r < 4; r++)
            rmax[r] = fmaxf(rmax[r], __shfl_xor(rmax[r], off, 16));
    if (coll == 0)
#pragma unroll
        for (int r = 0; r < 4; r++)
            out[(bL + m0 + q * 4 + r) * 128 + 32 + dir * 16 + p] = rmax[r];
}

extern "C" void kernel_launch(void* const* d_in, const int* in_sizes, int n_in,
                              void* d_out, int out_size, void* d_ws, size_t ws_size,
                              hipStream_t stream) {
    const float* q1 = (const float*)d_in[0];
    const float* q2 = (const float*)d_in[1];
    const float* W  = (const float*)d_in[2];
    float* out = (float*)d_out;

    float* ws = (float*)d_ws;
    float* attsum = ws;                               // B*L
    float* att_fw = attsum + B * L;                   // B*L*L
    float* att_bw = att_fw + (size_t)B * L * L;
    float* mean_fw = att_bw + (size_t)B * L * L;      // B*L*H each below
    float* mean_bw = mean_fw + (size_t)B * L * H;
    float* maxat_fw = mean_bw + (size_t)B * L * H;
    float* maxat_bw = maxat_fw + (size_t)B * L * H;

    hipMemsetAsync(attsum, 0, B * L * sizeof(float), stream);
    k_maxpool_v2<<<dim3(B * 2, P, 2), 256, 0, stream>>>(q1, q2, W, out);
    k_att_v3<<<dim3(B * 2, 8, 8), 64, 0, stream>>>(q1, q2, att_fw, att_bw, attsum);
    k_meanmax_v3<<<dim3(B * 2, 32), 256, 0, stream>>>(q2, att_fw, att_bw, attsum,
                                                      mean_fw, mean_bw, maxat_fw, maxat_bw);
    k_cosfull_v3<<<dim3(B * 16, 6), 256, 0, stream>>>(q1, q2, mean_fw, mean_bw,
                                                      maxat_fw, maxat_bw, W, out);
}